// Round 16
// baseline (238.651 us; speedup 1.0000x reference)
//
#include <hip/hip_runtime.h>
#include <cstdint>

typedef unsigned short u16;
typedef short s8v __attribute__((ext_vector_type(8)));
typedef float f4v __attribute__((ext_vector_type(4)));

// fp32 -> bf16 round-to-nearest-even (bit trick)
__device__ __forceinline__ u16 f2b(float f) {
  uint32_t u = __float_as_uint(f);
  u = (u + 0x7FFFu + ((u >> 16) & 1u)) >> 16;
  return (u16)u;
}

// pack two f32 -> bf16x2 (RNE) in one instruction (T12 recipe; no builtin)
__device__ __forceinline__ uint32_t pk2(float a, float b) {
  uint32_t r;
  asm("v_cvt_pk_bf16_f32 %0, %1, %2" : "=v"(r) : "v"(a), "v"(b));
  return r;
}

// async global->LDS, 16B per lane (wave-uniform LDS base + lane*16 layout)
__device__ __forceinline__ void gload16(const u16* g, u16* l) {
  __builtin_amdgcn_global_load_lds(
      (const __attribute__((address_space(1))) void*)g,
      (__attribute__((address_space(3))) void*)l, 16, 0, 0);
}

// ---------------------------------------------------------------------------
// Fused prep kernel
// blocks: [0,4096) conv_x | [4096,4864) convT_w | [4864,5120) convT_wo |
//         [5120,5136) conv_bias
// ---------------------------------------------------------------------------
__global__ void prep(const float* __restrict__ x, u16* __restrict__ xb,
                     const float* __restrict__ WQ, const float* __restrict__ WK,
                     const float* __restrict__ WV, const float* __restrict__ WO,
                     u16* __restrict__ WTqkv, u16* __restrict__ WOT,
                     const float* __restrict__ bQ, const float* __restrict__ bK,
                     const float* __restrict__ bV, const float* __restrict__ bO,
                     float* __restrict__ bqkv, float* __restrict__ bsum) {
  __shared__ u16 tile[64][65];
  const int bid = blockIdx.x;
  const int tid = threadIdx.x;

  if (bid < 4096) {                       // x fp32 -> bf16, 4 elems/thread
    int i = bid * 256 + tid;
    float4 v = ((const float4*)x)[i];
    uint2 o;
    o.x = (uint32_t)f2b(v.x) | ((uint32_t)f2b(v.y) << 16);
    o.y = (uint32_t)f2b(v.z) | ((uint32_t)f2b(v.w) << 16);
    ((uint2*)xb)[i] = o;
  } else if (bid < 4864) {                // W_{Q,K,V} -> WTqkv (B^T), 64x64 transpose
    int sub = bid - 4096;
    int w = sub >> 8, sub2 = sub & 255;
    const float* W = (w == 0) ? WQ : (w == 1) ? WK : WV;
    u16* dst = WTqkv + (size_t)w * 1024 * 1024;
    const int m0 = (sub2 & 15) * 64;
    const int h  = sub2 >> 4;
    const int c  = tid & 63;
    const int r4 = tid >> 6;
    const float* Wh = W + (size_t)h * 65536;
    for (int i = 0; i < 16; ++i) {
      int lm = i * 4 + r4;
      tile[lm][c] = f2b(Wh[(size_t)(m0 + lm) * 64 + c]);
    }
    __syncthreads();
    for (int i = 0; i < 16; ++i) {
      int dd = i * 4 + r4;
      dst[((size_t)h * 64 + dd) * 1024 + m0 + c] = tile[c][dd];
    }
  } else if (bid < 5120) {                // W_O flat [1024][1024] -> WOT[m][k]
    int sub = bid - 4864;
    const int k0 = (sub & 15) * 64;
    const int m0 = (sub >> 4) * 64;
    const int c  = tid & 63;
    const int r4 = tid >> 6;
    for (int i = 0; i < 16; ++i) {
      int lk = i * 4 + r4;
      tile[lk][c] = f2b(WO[(size_t)(k0 + lk) * 1024 + m0 + c]);
    }
    __syncthreads();
    for (int i = 0; i < 16; ++i) {
      int lm = i * 4 + r4;
      WOT[(size_t)(m0 + lm) * 1024 + k0 + c] = tile[c][lm];
    }
  } else {                                // biases
    int t = (bid - 5120) * 256 + tid;
    if (t < 1024)       bqkv[t] = bQ[t];
    else if (t < 2048)  bqkv[t] = bK[t - 1024];
    else if (t < 3072)  bqkv[t] = bV[t - 2048];
    else {
      int m = t - 3072;
      float s = 0.f;
      for (int hh = 0; hh < 16; ++hh) s += bO[hh * 1024 + m];
      bsum[m] = s;
    }
  }
}

// ---------------------------------------------------------------------------
// bf16 MFMA GEMM: C = (A * BT^T + bias[col]) * (col<scale_cols ? 0.125 : 1)
// BMxBN tile, BK in {32,64}, NTHR/64 waves, per-wave 64x(BN/2). BK=64 staged
// as two BK=32 half-tiles (wave-uniform-dest rule preserved). 2-phase
// pipeline: STAGE(next) before ds_read+MFMA of current, one barrier/K-step.
// FUSE_VT (QKV proj): blocks with n0 >= 2048 emit V columns TRANSPOSED to
// VTout[(h*64+d)][token] via an LDS bounce (stride 136).
// ---------------------------------------------------------------------------
template<bool OUT_F32, int BM, int BN, int NTHR, bool FUSE_VT, int BK>
__global__ void gemm_bt(const u16* __restrict__ A, const u16* __restrict__ BT,
                        const float* __restrict__ bias, void* __restrict__ Cout,
                        u16* __restrict__ VTout, int N, int K, int scale_cols) {
  constexpr int NW = NTHR / 64;
  constexpr int WM = NW / 2;
  constexpr int NJ = BN / 32;
  constexpr int NH = BK / 32;            // half-tiles per K-step
  constexpr int ASEG = BM * 4 / NTHR;
  constexpr int BSEG = BN * 4 / NTHR;
  constexpr int STG_U16 = 2 * NH * (BM + BN) * 32;
  constexpr int CT_STRIDE = BM + 8;
  constexpr int SMEM_U16 = (FUSE_VT && BN * CT_STRIDE > STG_U16)
                               ? BN * CT_STRIDE : STG_U16;
  static_assert(BM / WM == 64, "per-wave rows must be 64");
  static_assert(BM * 4 % NTHR == 0 && BN * 4 % NTHR == 0, "staging divisibility");

  __shared__ __align__(16) u16 smem[SMEM_U16];
  u16* sA = smem;                        // [2][NH][BM*32]
  u16* sB = smem + 2 * NH * BM * 32;     // [2][NH][BN*32]

  const int tid  = threadIdx.x;
  const int lane = tid & 63, wave = tid >> 6;
  const int wm = wave >> 1, wn = wave & 1;
  const int lq = lane & 15, quad = lane >> 4;
  const int m0 = blockIdx.y * BM, n0 = blockIdx.x * BN;

  f4v acc[4][NJ] = {};

  auto STAGE = [&](int buf, int k0) {
    for (int hh = 0; hh < NH; ++hh) {
      for (int i = 0; i < ASEG; ++i) {
        int s = tid + i * NTHR;
        int row = s >> 2, part = s & 3;
        gload16(A + (size_t)(m0 + row) * K + k0 + hh * 32 + part * 8,
                &sA[(buf * NH + hh) * BM * 32 + s * 8]);
      }
      for (int i = 0; i < BSEG; ++i) {
        int s = tid + i * NTHR;
        int row = s >> 2, part = s & 3;
        gload16(BT + (size_t)(n0 + row) * K + k0 + hh * 32 + part * 8,
                &sB[(buf * NH + hh) * BN * 32 + s * 8]);
      }
    }
  };

  STAGE(0, 0);
  __syncthreads();                       // compiler drains vmcnt before barrier
  int cur = 0;
  for (int k0 = 0; k0 < K; k0 += BK) {
    if (k0 + BK < K) STAGE(cur ^ 1, k0 + BK);   // issue next-tile loads FIRST
    for (int hh = 0; hh < NH; ++hh) {
      s8v af[4], bfr[NJ];
      for (int i = 0; i < 4; ++i)
        af[i]  = *(const s8v*)&sA[(cur * NH + hh) * BM * 32 +
                                  (wm * 64 + i * 16 + lq) * 32 + quad * 8];
      for (int j = 0; j < NJ; ++j)
        bfr[j] = *(const s8v*)&sB[(cur * NH + hh) * BN * 32 +
                                  (wn * (BN / 2) + j * 16 + lq) * 32 + quad * 8];
      for (int i = 0; i < 4; ++i)
        for (int j = 0; j < NJ; ++j)
          acc[i][j] = __builtin_amdgcn_mfma_f32_16x16x32_bf16(af[i], bfr[j], acc[i][j], 0, 0, 0);
    }
    __syncthreads();                     // next-tile loads overlapped the MFMAs
    cur ^= 1;
  }

  if (FUSE_VT && n0 >= 2048) {
    const int vcol0 = n0 - 2048;
    u16* ct = smem;                      // staging LDS dead past final barrier
    for (int i = 0; i < 4; ++i)
      for (int j = 0; j < NJ; ++j) {
        int row = wm * 64 + i * 16 + quad * 4;
        int col = wn * (BN / 2) + j * 16 + lq;
        float bb = bias[n0 + col];       // V cols: no 0.125 scale
        uint2 w;
        w.x = pk2(acc[i][j][0] + bb, acc[i][j][1] + bb);
        w.y = pk2(acc[i][j][2] + bb, acc[i][j][3] + bb);
        *(uint2*)&ct[col * CT_STRIDE + row] = w;
      }
    __syncthreads();
    if (tid < BN * 2) {
      int cc = tid >> 1, half = tid & 1;
      const uint4* src = (const uint4*)&ct[cc * CT_STRIDE + half * (BM / 2)];
      uint4* dst = (uint4*)&VTout[(size_t)(vcol0 + cc) * 4096 + m0 + half * (BM / 2)];
#pragma unroll
      for (int k = 0; k < BM / 16; ++k) dst[k] = src[k];
    }
    return;
  }

  for (int i = 0; i < 4; ++i)
    for (int j = 0; j < NJ; ++j) {
      int row = m0 + wm * 64 + i * 16 + quad * 4;
      int col = n0 + wn * (BN / 2) + j * 16 + lq;
      float bb = bias[col];
      float sc = (col < scale_cols) ? 0.125f : 1.0f;
      for (int r = 0; r < 4; ++r) {
        float v = (acc[i][j][r] + bb) * sc;
        if (OUT_F32) ((float*)Cout)[(size_t)(row + r) * N + col] = v;
        else         ((u16*)Cout)[(size_t)(row + r) * N + col] = f2b(v);
      }
    }
}

// ---------------------------------------------------------------------------
// Flash attention (causal). 1 wave, 2 adjacent 16-query tiles, KVBLK=64.
// Round-16: 2-DEEP pipeline (T15): iteration c issues QK(c) + PV(c-2)
// (matrix pipe; P(c-2) written 2 iters ago -> ds_read latency-free), then
// loads, then SMW(c-1) -- whose QK(c-1) inputs are long available, so the
// ~400cy exp/VALU chain executes WHILE the 32 in-flight MFMAs drain.
// Ordering exactness: PV(c-2) adds at scale m(c-2) BEFORE SMW(c-1) rescales
// z to m(c-1) (online-softmax algebra preserved; hand-verified nchunk=1,2,3).
// P ping-pong: SMW(c-1) writes buf (c-1)&1, PV(c-2) reads buf c&1 -- disjoint
// within an iteration; end-of-iteration fence pins cross-iteration order.
// V: 2-buffer parity (vfA even / vfB odd chunks), consumed-then-reloaded in
// the same iteration, named buffers via 2-unrolled loop (rule #20 safe).
// Everything else = round-13 proven config (2 tiles/wave is the measured
// optimum: 1t=160us, 2t=71us, 4t=101us).
// ---------------------------------------------------------------------------
__global__ __launch_bounds__(64, 2) void attn_fwd(const u16* __restrict__ QKV,
                                                  const u16* __restrict__ VT,
                                                  u16* __restrict__ Z) {
  __shared__ __align__(16) u16 sP[2][2][16 * 72];   // [tile][pingpong]
  const int lane = threadIdx.x;
  const int lq = lane & 15, quad = lane >> 4;

  const int id   = blockIdx.x;             // 0..2047
  const int xcd  = id & 7;
  const int slot = id >> 3;                // 0..255 per XCD
  const int g    = xcd + 8 * (slot >> 6);  // combo 0..31
  const int s    = slot & 63;
  const int u    = (s < 32) ? (63 - s) : (s - 32);  // heavy+light pairing
  const int h = g & 15, b = g >> 4;
  const int qA = u * 32, qB = qA + 16;
  const int nchunk = u / 2 + 1;            // 64-key chunks

  const int RS = 3072;
  const u16* base = QKV + (size_t)b * 2048 * RS;
  const u16* Qb  = base + h * 64;
  const u16* Kb  = base + 1024 + h * 64;
  const u16* VTb = VT + (size_t)h * 64 * 4096 + (size_t)b * 2048;

  // Q frags (B-operand): lane holds Q[q+lq][d = 32*half + quad*8 + j]
  s8v qfA0 = *(const s8v*)&Qb[(size_t)(qA + lq) * RS + quad * 8];
  s8v qfA1 = *(const s8v*)&Qb[(size_t)(qA + lq) * RS + 32 + quad * 8];
  s8v qfB0 = *(const s8v*)&Qb[(size_t)(qB + lq) * RS + quad * 8];
  s8v qfB1 = *(const s8v*)&Qb[(size_t)(qB + lq) * RS + 32 + quad * 8];

  f4v zA[4] = {}, zB[4] = {};
  float mA = -3.0e38f, lA = 0.f, mB = -3.0e38f, lB = 0.f;

  s8v kf[8];             // K of the current chunk (consumed at QK issue)
  s8v vfA[8], vfB[8];    // V parity buffers: even chunks vfA, odd vfB
  // score state: parity a-sets (even chunks in aX*, odd in aY*)
  f4v aXA[4] = {}, aXB[4] = {}, aYA[4] = {}, aYB[4] = {};

#define LOADK(c_) do {                                                        \
    const int kk0_ = (c_) * 64;                                               \
    _Pragma("unroll")                                                         \
    for (int i_ = 0; i_ < 4; ++i_) {                                          \
      const u16* kr_ = &Kb[(size_t)(kk0_ + 16 * i_ + lq) * RS + quad * 8];    \
      kf[2 * i_]     = *(const s8v*)kr_;                                      \
      kf[2 * i_ + 1] = *(const s8v*)(kr_ + 32);                               \
    }                                                                         \
  } while (0)

  auto LOADV = [&](int c_, s8v (&vv)[8]) {
#pragma unroll
    for (int d_ = 0; d_ < 4; ++d_) {
      const u16* vr_ = &VTb[(size_t)(d_ * 16 + lq) * 4096 + c_ * 64 + quad * 8];
      vv[d_]     = *(const s8v*)vr_;
      vv[d_ + 4] = *(const s8v*)(vr_ + 32);
    }
  };

  // softmax of 64-key chunk c for one tile (swapped layout) + packed P write
  auto SMW = [&](int c, int qt0, float& mrow, float& lsum, f4v (&zacc)[4],
                 u16* sPt, f4v (&sc)[4]) {
    float sv[4][4];
    for (int i = 0; i < 4; ++i)
      for (int r = 0; r < 4; ++r) sv[i][r] = sc[i][r];
    if (c + 1 == nchunk) {              // only the last chunk crosses the diagonal
      const int kb = c * 64;
      for (int i = 0; i < 4; ++i)
        for (int r = 0; r < 4; ++r)
          if (kb + 16 * i + quad * 4 + r > qt0 + lq) sv[i][r] = -3.0e38f;
    }
    float lmax = sv[0][0];
    for (int i = 0; i < 4; ++i)
      for (int r = 0; r < 4; ++r) lmax = fmaxf(lmax, sv[i][r]);
    if (!__all(lmax <= mrow + 8.0f)) {  // defer-max, THR=8
      float t = lmax;
      t = fmaxf(t, __shfl_xor(t, 16, 64));
      t = fmaxf(t, __shfl_xor(t, 32, 64));
      float mnew = fmaxf(mrow, t);
      float al = __expf(mrow - mnew);
      mrow = mnew;
      lsum *= al;
      float alr[4];
      for (int r = 0; r < 4; ++r) alr[r] = __shfl(al, quad * 4 + r, 16);
      for (int dc = 0; dc < 4; ++dc)
        for (int r = 0; r < 4; ++r) zacc[dc][r] *= alr[r];
    }
    float acc = 0.f;
    float p[4][4];
    for (int i = 0; i < 4; ++i)
      for (int r = 0; r < 4; ++r) {
        p[i][r] = __expf(sv[i][r] - mrow);
        acc += p[i][r];
      }
    lsum += acc;
    for (int i = 0; i < 4; ++i) {
      uint2 w;
      w.x = pk2(p[i][0], p[i][1]);
      w.y = pk2(p[i][2], p[i][3]);
      *(uint2*)&sPt[lq * 72 + 16 * i + quad * 4] = w;
    }
  };

#define QK(aA_, aB_) do {                                                     \
    _Pragma("unroll")                                                         \
    for (int i_ = 0; i_ < 4; ++i_) {                                          \
      aA_[i_] = __builtin_amdgcn_mfma_f32_16x16x32_bf16(kf[2*i_],   qfA0, aA_[i_], 0, 0, 0); \
      aA_[i_] = __builtin_amdgcn_mfma_f32_16x16x32_bf16(kf[2*i_+1], qfA1, aA_[i_], 0, 0, 0); \
      aB_[i_] = __builtin_amdgcn_mfma_f32_16x16x32_bf16(kf[2*i_],   qfB0, aB_[i_], 0, 0, 0); \
      aB_[i_] = __builtin_amdgcn_mfma_f32_16x16x32_bf16(kf[2*i_+1], qfB1, aB_[i_], 0, 0, 0); \
    }                                                                         \
  } while (0)

  // PV from P buffer pb + given V parity buffer
  auto PV = [&](int pb, s8v (&vv)[8]) {
    s8v pA0 = *(const s8v*)&sP[0][pb][lq * 72 + quad * 8];
    s8v pA1 = *(const s8v*)&sP[0][pb][lq * 72 + 32 + quad * 8];
    s8v pB0 = *(const s8v*)&sP[1][pb][lq * 72 + quad * 8];
    s8v pB1 = *(const s8v*)&sP[1][pb][lq * 72 + 32 + quad * 8];
#pragma unroll
    for (int d_ = 0; d_ < 4; ++d_) {
      zA[d_] = __builtin_amdgcn_mfma_f32_16x16x32_bf16(pA0, vv[d_],     zA[d_], 0, 0, 0);
      zA[d_] = __builtin_amdgcn_mfma_f32_16x16x32_bf16(pA1, vv[d_ + 4], zA[d_], 0, 0, 0);
      zB[d_] = __builtin_amdgcn_mfma_f32_16x16x32_bf16(pB0, vv[d_],     zB[d_], 0, 0, 0);
      zB[d_] = __builtin_amdgcn_mfma_f32_16x16x32_bf16(pB1, vv[d_ + 4], zB[d_], 0, 0, 0);
    }
  };

  // pipeline step at chunk c: QK(c) || PV(c-2) || SMW(c-1).
  // cur* receive chunk-c scores; prv* hold chunk-(c-1) scores; vfc is the
  // parity buffer of c (holds V(c-2) on entry, reloaded with V(c)).
  auto STEP = [&](int c, f4v (&cA)[4], f4v (&cB)[4],
                  f4v (&pA)[4], f4v (&pB)[4], s8v (&vfc)[8]) {
#pragma unroll
    for (int i = 0; i < 4; ++i) { cA[i] = (f4v){}; cB[i] = (f4v){}; }
    __builtin_amdgcn_s_setprio(1);
    QK(cA, cB);                         // kf = K(c), consumed at issue
    if (c >= 2) PV(c & 1, vfc);         // PV(c-2): P buf (c-2)&1 == c&1
    __builtin_amdgcn_s_setprio(0);
    if (c + 1 < nchunk) LOADK(c + 1);   // kf free after QK issue
    LOADV(c, vfc);                      // vfc free after PV issue
    SMW(c - 1, qA, mA, lA, zA, sP[0][(c - 1) & 1], pA);
    SMW(c - 1, qB, mB, lB, zB, sP[1][(c - 1) & 1], pB);
    asm volatile("" ::: "memory");      // P(c-1) writes pinned before later PV
  };

  LOADK(0);
  { // chunk 0: QK only (SMW(0) deferred into the pipeline)
    __builtin_amdgcn_s_setprio(1);
    QK(aXA, aXB);
    __builtin_amdgcn_s_setprio(0);
    if (nchunk > 1) LOADK(1);
    LOADV(0, vfA);
  }

  int c = 1;
  for (; c + 1 < nchunk; c += 2) {
    STEP(c,     aYA, aYB, aXA, aXB, vfB);   // odd chunk
    STEP(c + 1, aXA, aXB, aYA, aYB, vfA);   // even chunk
  }
  if (c < nchunk)                            // tail (c odd == nchunk-1)
    STEP(c, aYA, aYB, aXA, aXB, vfB);

  { // drain: L = nchunk-1. pending: PV(L-1), SMW(L), PV(L).
    const int L = nchunk - 1;
    if (L >= 1) {
      __builtin_amdgcn_s_setprio(1);
      if (L & 1) PV((L + 1) & 1, vfA);  // V(L-1) even -> vfA
      else       PV((L + 1) & 1, vfB);  // V(L-1) odd  -> vfB
      __builtin_amdgcn_s_setprio(0);
      asm volatile("" ::: "memory");
    }
    if (L & 1) {
      SMW(L, qA, mA, lA, zA, sP[0][L & 1], aYA);
      SMW(L, qB, mB, lB, zB, sP[1][L & 1], aYB);
    } else {
      SMW(L, qA, mA, lA, zA, sP[0][L & 1], aXA);
      SMW(L, qB, mB, lB, zB, sP[1][L & 1], aXB);
    }
    asm volatile("" ::: "memory");
    __builtin_amdgcn_s_setprio(1);
    if (L & 1) PV(L & 1, vfB);
    else       PV(L & 1, vfA);
    __builtin_amdgcn_s_setprio(0);
  }
#undef QK
#undef LOADK

  // one-time sum reduction across the 4 quad-lanes of each row
  lA += __shfl_xor(lA, 16, 64); lA += __shfl_xor(lA, 32, 64);
  lB += __shfl_xor(lB, 16, 64); lB += __shfl_xor(lB, 32, 64);
  float invA[4], invB[4];
  for (int r = 0; r < 4; ++r) {
    invA[r] = 1.0f / __shfl(lA, quad * 4 + r, 16);
    invB[r] = 1.0f / __shfl(lB, quad * 4 + r, 16);
  }
  for (int dc = 0; dc < 4; ++dc)
    for (int r = 0; r < 4; ++r) {
      size_t rowA = (size_t)b * 2048 + qA + quad * 4 + r;
      size_t rowB = (size_t)b * 2048 + qB + quad * 4 + r;
      Z[rowA * 1024 + h * 64 + dc * 16 + lq] = f2b(zA[dc][r] * invA[r]);
      Z[rowB * 1024 + h * 64 + dc * 16 + lq] = f2b(zB[dc][r] * invB[r]);
    }
}

// ---------------------------------------------------------------------------
// Launch
// ---------------------------------------------------------------------------
extern "C" void kernel_launch(void* const* d_in, const int* in_sizes, int n_in,
                              void* d_out, int out_size, void* d_ws, size_t ws_size,
                              hipStream_t stream) {
  const float* x  = (const float*)d_in[0];
  const float* WQ = (const float*)d_in[1];
  const float* bQ = (const float*)d_in[2];
  const float* WK = (const float*)d_in[3];
  const float* bK = (const float*)d_in[4];
  const float* WV = (const float*)d_in[5];
  const float* WO = (const float*)d_in[6];
  const float* bV = (const float*)d_in[7];
  const float* bO = (const float*)d_in[8];
  float* out = (float*)d_out;

  uint8_t* ws = (uint8_t*)d_ws;
  u16*   xb    = (u16*)(ws);                       //  8 MB  [4096][1024] bf16 x
  u16*   WTqkv = (u16*)(ws + 8388608);             //  6 MB
  u16*   WOT   = (u16*)(ws + 14680064);            //  2 MB
  u16*   QKV   = (u16*)(ws + 16777216);            // 24 MB (V third unused)
  u16*   Zb    = (u16*)(ws + 41943040);            //  8 MB
  float* bqkv  = (float*)(ws + 50331648);          // 12 KB
  float* bsum  = (float*)(ws + 50343936);          //  4 KB
  u16*   VTv   = (u16*)(ws + 50348032);            //  8 MB V^T (own region)

  // fused prep: conv_x + 3x convT_w + convT_wo + conv_bias
  prep<<<5136, 256, 0, stream>>>(x, xb, WQ, WK, WV, WO, WTqkv, WOT,
                                 bQ, bK, bV, bO, bqkv, bsum);
  // QKV projection (Q cols pre-scaled by 0.125), fused V-transpose epilogue:
  // 128x128 tile, BK=32, 768 blocks = exactly 3/CU
  gemm_bt<false, 128, 128, 256, true, 32><<<dim3(24, 32), 256, 0, stream>>>(
      xb, WTqkv, bqkv, (void*)QKV, VTv, 3072, 1024, 1024);
  // attention: 2048 one-wave blocks, 2-deep pipelined
  attn_fwd<<<dim3(2048, 1, 1), 64, 0, stream>>>(QKV, VTv, Zb);
  // output projection: 128x64 tile, BK=64 (2 half-stages), 512 blocks = 2/CU
  gemm_bt<true, 128, 64, 256, false, 64><<<dim3(16, 32), 256, 0, stream>>>(
      Zb, WOT, bsum, (void*)out, nullptr, 1024, 1024, 0);
}

// Round 17
// 207.223 us; speedup vs baseline: 1.1517x; 1.1517x over previous
//
#include <hip/hip_runtime.h>
#include <cstdint>

typedef unsigned short u16;
typedef short s8v __attribute__((ext_vector_type(8)));
typedef float f4v __attribute__((ext_vector_type(4)));

// fp32 -> bf16 round-to-nearest-even (bit trick)
__device__ __forceinline__ u16 f2b(float f) {
  uint32_t u = __float_as_uint(f);
  u = (u + 0x7FFFu + ((u >> 16) & 1u)) >> 16;
  return (u16)u;
}

// pack two f32 -> bf16x2 (RNE) in one instruction (T12 recipe; no builtin)
__device__ __forceinline__ uint32_t pk2(float a, float b) {
  uint32_t r;
  asm("v_cvt_pk_bf16_f32 %0, %1, %2" : "=v"(r) : "v"(a), "v"(b));
  return r;
}

// async global->LDS, 16B per lane (wave-uniform LDS base + lane*16 layout)
__device__ __forceinline__ void gload16(const u16* g, u16* l) {
  __builtin_amdgcn_global_load_lds(
      (const __attribute__((address_space(1))) void*)g,
      (__attribute__((address_space(3))) void*)l, 16, 0, 0);
}

// ---------------------------------------------------------------------------
// Fused prep kernel
// blocks: [0,4096) conv_x | [4096,4864) convT_w | [4864,5120) convT_wo |
//         [5120,5136) conv_bias
// ---------------------------------------------------------------------------
__global__ void prep(const float* __restrict__ x, u16* __restrict__ xb,
                     const float* __restrict__ WQ, const float* __restrict__ WK,
                     const float* __restrict__ WV, const float* __restrict__ WO,
                     u16* __restrict__ WTqkv, u16* __restrict__ WOT,
                     const float* __restrict__ bQ, const float* __restrict__ bK,
                     const float* __restrict__ bV, const float* __restrict__ bO,
                     float* __restrict__ bqkv, float* __restrict__ bsum) {
  __shared__ u16 tile[64][65];
  const int bid = blockIdx.x;
  const int tid = threadIdx.x;

  if (bid < 4096) {                       // x fp32 -> bf16, 4 elems/thread
    int i = bid * 256 + tid;
    float4 v = ((const float4*)x)[i];
    uint2 o;
    o.x = (uint32_t)f2b(v.x) | ((uint32_t)f2b(v.y) << 16);
    o.y = (uint32_t)f2b(v.z) | ((uint32_t)f2b(v.w) << 16);
    ((uint2*)xb)[i] = o;
  } else if (bid < 4864) {                // W_{Q,K,V} -> WTqkv (B^T), 64x64 transpose
    int sub = bid - 4096;
    int w = sub >> 8, sub2 = sub & 255;
    const float* W = (w == 0) ? WQ : (w == 1) ? WK : WV;
    u16* dst = WTqkv + (size_t)w * 1024 * 1024;
    const int m0 = (sub2 & 15) * 64;
    const int h  = sub2 >> 4;
    const int c  = tid & 63;
    const int r4 = tid >> 6;
    const float* Wh = W + (size_t)h * 65536;
    for (int i = 0; i < 16; ++i) {
      int lm = i * 4 + r4;
      tile[lm][c] = f2b(Wh[(size_t)(m0 + lm) * 64 + c]);
    }
    __syncthreads();
    for (int i = 0; i < 16; ++i) {
      int dd = i * 4 + r4;
      dst[((size_t)h * 64 + dd) * 1024 + m0 + c] = tile[c][dd];
    }
  } else if (bid < 5120) {                // W_O flat [1024][1024] -> WOT[m][k]
    int sub = bid - 4864;
    const int k0 = (sub & 15) * 64;
    const int m0 = (sub >> 4) * 64;
    const int c  = tid & 63;
    const int r4 = tid >> 6;
    for (int i = 0; i < 16; ++i) {
      int lk = i * 4 + r4;
      tile[lk][c] = f2b(WO[(size_t)(k0 + lk) * 1024 + m0 + c]);
    }
    __syncthreads();
    for (int i = 0; i < 16; ++i) {
      int lm = i * 4 + r4;
      WOT[(size_t)(m0 + lm) * 1024 + k0 + c] = tile[c][lm];
    }
  } else {                                // biases
    int t = (bid - 5120) * 256 + tid;
    if (t < 1024)       bqkv[t] = bQ[t];
    else if (t < 2048)  bqkv[t] = bK[t - 1024];
    else if (t < 3072)  bqkv[t] = bV[t - 2048];
    else {
      int m = t - 3072;
      float s = 0.f;
      for (int hh = 0; hh < 16; ++hh) s += bO[hh * 1024 + m];
      bsum[m] = s;
    }
  }
}

// ---------------------------------------------------------------------------
// bf16 MFMA GEMM: C = (A * BT^T + bias[col]) * (col<scale_cols ? 0.125 : 1)
// BMxBN tile, BK in {32,64}, NTHR/64 waves, per-wave 64x(BN/2). BK=64 staged
// as two BK=32 half-tiles (wave-uniform-dest rule preserved). 2-phase
// pipeline: STAGE(next) before ds_read+MFMA of current, one barrier/K-step.
// FUSE_VT (QKV proj): blocks with n0 >= 2048 emit V columns TRANSPOSED to
// VTout[(h*64+d)][token] via an LDS bounce (stride 136).
// ---------------------------------------------------------------------------
template<bool OUT_F32, int BM, int BN, int NTHR, bool FUSE_VT, int BK>
__global__ void gemm_bt(const u16* __restrict__ A, const u16* __restrict__ BT,
                        const float* __restrict__ bias, void* __restrict__ Cout,
                        u16* __restrict__ VTout, int N, int K, int scale_cols) {
  constexpr int NW = NTHR / 64;
  constexpr int WM = NW / 2;
  constexpr int NJ = BN / 32;
  constexpr int NH = BK / 32;            // half-tiles per K-step
  constexpr int ASEG = BM * 4 / NTHR;
  constexpr int BSEG = BN * 4 / NTHR;
  constexpr int STG_U16 = 2 * NH * (BM + BN) * 32;
  constexpr int CT_STRIDE = BM + 8;
  constexpr int SMEM_U16 = (FUSE_VT && BN * CT_STRIDE > STG_U16)
                               ? BN * CT_STRIDE : STG_U16;
  static_assert(BM / WM == 64, "per-wave rows must be 64");
  static_assert(BM * 4 % NTHR == 0 && BN * 4 % NTHR == 0, "staging divisibility");

  __shared__ __align__(16) u16 smem[SMEM_U16];
  u16* sA = smem;                        // [2][NH][BM*32]
  u16* sB = smem + 2 * NH * BM * 32;     // [2][NH][BN*32]

  const int tid  = threadIdx.x;
  const int lane = tid & 63, wave = tid >> 6;
  const int wm = wave >> 1, wn = wave & 1;
  const int lq = lane & 15, quad = lane >> 4;
  const int m0 = blockIdx.y * BM, n0 = blockIdx.x * BN;

  f4v acc[4][NJ] = {};

  auto STAGE = [&](int buf, int k0) {
    for (int hh = 0; hh < NH; ++hh) {
      for (int i = 0; i < ASEG; ++i) {
        int s = tid + i * NTHR;
        int row = s >> 2, part = s & 3;
        gload16(A + (size_t)(m0 + row) * K + k0 + hh * 32 + part * 8,
                &sA[(buf * NH + hh) * BM * 32 + s * 8]);
      }
      for (int i = 0; i < BSEG; ++i) {
        int s = tid + i * NTHR;
        int row = s >> 2, part = s & 3;
        gload16(BT + (size_t)(n0 + row) * K + k0 + hh * 32 + part * 8,
                &sB[(buf * NH + hh) * BN * 32 + s * 8]);
      }
    }
  };

  STAGE(0, 0);
  __syncthreads();                       // compiler drains vmcnt before barrier
  int cur = 0;
  for (int k0 = 0; k0 < K; k0 += BK) {
    if (k0 + BK < K) STAGE(cur ^ 1, k0 + BK);   // issue next-tile loads FIRST
    for (int hh = 0; hh < NH; ++hh) {
      s8v af[4], bfr[NJ];
      for (int i = 0; i < 4; ++i)
        af[i]  = *(const s8v*)&sA[(cur * NH + hh) * BM * 32 +
                                  (wm * 64 + i * 16 + lq) * 32 + quad * 8];
      for (int j = 0; j < NJ; ++j)
        bfr[j] = *(const s8v*)&sB[(cur * NH + hh) * BN * 32 +
                                  (wn * (BN / 2) + j * 16 + lq) * 32 + quad * 8];
      for (int i = 0; i < 4; ++i)
        for (int j = 0; j < NJ; ++j)
          acc[i][j] = __builtin_amdgcn_mfma_f32_16x16x32_bf16(af[i], bfr[j], acc[i][j], 0, 0, 0);
    }
    __syncthreads();                     // next-tile loads overlapped the MFMAs
    cur ^= 1;
  }

  if (FUSE_VT && n0 >= 2048) {
    const int vcol0 = n0 - 2048;
    u16* ct = smem;                      // staging LDS dead past final barrier
    for (int i = 0; i < 4; ++i)
      for (int j = 0; j < NJ; ++j) {
        int row = wm * 64 + i * 16 + quad * 4;
        int col = wn * (BN / 2) + j * 16 + lq;
        float bb = bias[n0 + col];       // V cols: no 0.125 scale
        uint2 w;
        w.x = pk2(acc[i][j][0] + bb, acc[i][j][1] + bb);
        w.y = pk2(acc[i][j][2] + bb, acc[i][j][3] + bb);
        *(uint2*)&ct[col * CT_STRIDE + row] = w;
      }
    __syncthreads();
    if (tid < BN * 2) {
      int cc = tid >> 1, half = tid & 1;
      const uint4* src = (const uint4*)&ct[cc * CT_STRIDE + half * (BM / 2)];
      uint4* dst = (uint4*)&VTout[(size_t)(vcol0 + cc) * 4096 + m0 + half * (BM / 2)];
#pragma unroll
      for (int k = 0; k < BM / 16; ++k) dst[k] = src[k];
    }
    return;
  }

  for (int i = 0; i < 4; ++i)
    for (int j = 0; j < NJ; ++j) {
      int row = m0 + wm * 64 + i * 16 + quad * 4;
      int col = n0 + wn * (BN / 2) + j * 16 + lq;
      float bb = bias[col];
      float sc = (col < scale_cols) ? 0.125f : 1.0f;
      for (int r = 0; r < 4; ++r) {
        float v = (acc[i][j][r] + bb) * sc;
        if (OUT_F32) ((float*)Cout)[(size_t)(row + r) * N + col] = v;
        else         ((u16*)Cout)[(size_t)(row + r) * N + col] = f2b(v);
      }
    }
}

// ---------------------------------------------------------------------------
// Flash attention (causal). 1 wave, 2 adjacent 16-query tiles, KVBLK=64.
// FINAL: round-13 proven config (attn 71us, best of 10 structural variants).
// Measured axis map: tiles/wave {1:160, 2:71, 4:101}; KVBLK {32~=64};
// pipeline depth {1:71, 2:spill at 2-tile VGPR budget}; split-K 86 (worse);
// launch_bounds must not cap below natural VGPR (round-8: (64,4) -> spill).
// Heavy+light CU pairing, XCD swizzle (FETCH 68->12MB), single K/V register
// buffers reloaded after MFMA consumption, ping-pong P LDS with compiler
// fences, setprio around MFMA clusters, defer-max THR=8, packed P via
// v_cvt_pk_bf16_f32, per-lane deferred sum.
// ---------------------------------------------------------------------------
__global__ __launch_bounds__(64, 2) void attn_fwd(const u16* __restrict__ QKV,
                                                  const u16* __restrict__ VT,
                                                  u16* __restrict__ Z) {
  __shared__ __align__(16) u16 sP[2][2][16 * 72];   // [tile][pingpong]
  const int lane = threadIdx.x;
  const int lq = lane & 15, quad = lane >> 4;

  const int id   = blockIdx.x;             // 0..2047
  const int xcd  = id & 7;
  const int slot = id >> 3;                // 0..255 per XCD
  const int g    = xcd + 8 * (slot >> 6);  // combo 0..31
  const int s    = slot & 63;
  const int u    = (s < 32) ? (63 - s) : (s - 32);  // heavy+light pairing
  const int h = g & 15, b = g >> 4;
  const int qA = u * 32, qB = qA + 16;
  const int nchunk = u / 2 + 1;            // 64-key chunks

  const int RS = 3072;
  const u16* base = QKV + (size_t)b * 2048 * RS;
  const u16* Qb  = base + h * 64;
  const u16* Kb  = base + 1024 + h * 64;
  const u16* VTb = VT + (size_t)h * 64 * 4096 + (size_t)b * 2048;

  // Q frags (B-operand): lane holds Q[q+lq][d = 32*half + quad*8 + j]
  s8v qfA0 = *(const s8v*)&Qb[(size_t)(qA + lq) * RS + quad * 8];
  s8v qfA1 = *(const s8v*)&Qb[(size_t)(qA + lq) * RS + 32 + quad * 8];
  s8v qfB0 = *(const s8v*)&Qb[(size_t)(qB + lq) * RS + quad * 8];
  s8v qfB1 = *(const s8v*)&Qb[(size_t)(qB + lq) * RS + 32 + quad * 8];

  f4v zA[4] = {}, zB[4] = {};
  float mA = -3.0e38f, lA = 0.f, mB = -3.0e38f, lB = 0.f;

  s8v kf[8], vf[8];   // single buffers: K rows / V cols of the current chunk

#define LOADK(c_) do {                                                        \
    const int kk0_ = (c_) * 64;                                               \
    _Pragma("unroll")                                                         \
    for (int i_ = 0; i_ < 4; ++i_) {                                          \
      const u16* kr_ = &Kb[(size_t)(kk0_ + 16 * i_ + lq) * RS + quad * 8];    \
      kf[2 * i_]     = *(const s8v*)kr_;                                      \
      kf[2 * i_ + 1] = *(const s8v*)(kr_ + 32);                               \
    }                                                                         \
  } while (0)

#define LOADV(c_) do {                                                        \
    const int kk0_ = (c_) * 64;                                               \
    _Pragma("unroll")                                                         \
    for (int d_ = 0; d_ < 4; ++d_) {                                          \
      const u16* vr_ = &VTb[(size_t)(d_ * 16 + lq) * 4096 + kk0_ + quad * 8]; \
      vf[d_]     = *(const s8v*)vr_;                                          \
      vf[d_ + 4] = *(const s8v*)(vr_ + 32);                                   \
    }                                                                         \
  } while (0)

  // softmax of 64-key chunk c for one tile (swapped layout) + packed P write
  auto SMW = [&](int c, int qt0, float& mrow, float& lsum, f4v (&zacc)[4],
                 u16* sPt, f4v (&sc)[4]) {
    float sv[4][4];
    for (int i = 0; i < 4; ++i)
      for (int r = 0; r < 4; ++r) sv[i][r] = sc[i][r];
    if (c + 1 == nchunk) {              // only the last chunk crosses the diagonal
      const int kb = c * 64;
      for (int i = 0; i < 4; ++i)
        for (int r = 0; r < 4; ++r)
          if (kb + 16 * i + quad * 4 + r > qt0 + lq) sv[i][r] = -3.0e38f;
    }
    float lmax = sv[0][0];
    for (int i = 0; i < 4; ++i)
      for (int r = 0; r < 4; ++r) lmax = fmaxf(lmax, sv[i][r]);
    if (!__all(lmax <= mrow + 8.0f)) {  // defer-max, THR=8
      float t = lmax;
      t = fmaxf(t, __shfl_xor(t, 16, 64));
      t = fmaxf(t, __shfl_xor(t, 32, 64));
      float mnew = fmaxf(mrow, t);
      float al = __expf(mrow - mnew);
      mrow = mnew;
      lsum *= al;
      float alr[4];
      for (int r = 0; r < 4; ++r) alr[r] = __shfl(al, quad * 4 + r, 16);
      for (int dc = 0; dc < 4; ++dc)
        for (int r = 0; r < 4; ++r) zacc[dc][r] *= alr[r];
    }
    float acc = 0.f;
    float p[4][4];
    for (int i = 0; i < 4; ++i)
      for (int r = 0; r < 4; ++r) {
        p[i][r] = __expf(sv[i][r] - mrow);
        acc += p[i][r];
      }
    lsum += acc;
    for (int i = 0; i < 4; ++i) {
      uint2 w;
      w.x = pk2(p[i][0], p[i][1]);
      w.y = pk2(p[i][2], p[i][3]);
      *(uint2*)&sPt[lq * 72 + 16 * i + quad * 4] = w;
    }
  };

#define QK(aA_, aB_) do {                                                     \
    _Pragma("unroll")                                                         \
    for (int i_ = 0; i_ < 4; ++i_) {                                          \
      aA_[i_] = __builtin_amdgcn_mfma_f32_16x16x32_bf16(kf[2*i_],   qfA0, aA_[i_], 0, 0, 0); \
      aA_[i_] = __builtin_amdgcn_mfma_f32_16x16x32_bf16(kf[2*i_+1], qfA1, aA_[i_], 0, 0, 0); \
      aB_[i_] = __builtin_amdgcn_mfma_f32_16x16x32_bf16(kf[2*i_],   qfB0, aB_[i_], 0, 0, 0); \
      aB_[i_] = __builtin_amdgcn_mfma_f32_16x16x32_bf16(kf[2*i_+1], qfB1, aB_[i_], 0, 0, 0); \
    }                                                                         \
  } while (0)

  // PV from ping-pong buffer pb (P of the previous chunk) + current vf
  auto PV = [&](int pb) {
    s8v pA0 = *(const s8v*)&sP[0][pb][lq * 72 + quad * 8];
    s8v pA1 = *(const s8v*)&sP[0][pb][lq * 72 + 32 + quad * 8];
    s8v pB0 = *(const s8v*)&sP[1][pb][lq * 72 + quad * 8];
    s8v pB1 = *(const s8v*)&sP[1][pb][lq * 72 + 32 + quad * 8];
#pragma unroll
    for (int d_ = 0; d_ < 4; ++d_) {
      zA[d_] = __builtin_amdgcn_mfma_f32_16x16x32_bf16(pA0, vf[d_],     zA[d_], 0, 0, 0);
      zA[d_] = __builtin_amdgcn_mfma_f32_16x16x32_bf16(pA1, vf[d_ + 4], zA[d_], 0, 0, 0);
      zB[d_] = __builtin_amdgcn_mfma_f32_16x16x32_bf16(pB0, vf[d_],     zB[d_], 0, 0, 0);
      zB[d_] = __builtin_amdgcn_mfma_f32_16x16x32_bf16(pB1, vf[d_ + 4], zB[d_], 0, 0, 0);
    }
  };

  LOADK(0);
  { // chunk 0: QK + softmax + P write into buf 0 (PV deferred)
    f4v aA[4] = {}, aB[4] = {};
    __builtin_amdgcn_s_setprio(1);
    QK(aA, aB);
    __builtin_amdgcn_s_setprio(0);
    if (nchunk > 1) LOADK(1);
    LOADV(0);
    SMW(0, qA, mA, lA, zA, sP[0][0], aA);
    SMW(0, qB, mB, lB, zB, sP[1][0], aB);
    asm volatile("" ::: "memory");      // P(0) writes pinned before PV reads
  }

  for (int c = 1; c < nchunk; ++c) {
    f4v aA[4] = {}, aB[4] = {};
    __builtin_amdgcn_s_setprio(1);
    QK(aA, aB);                         // kf = K(c)
    PV((c + 1) & 1);                    // reads P(c-1) + vf = V(c-1)
    __builtin_amdgcn_s_setprio(0);
    asm volatile("" ::: "memory");      // PV reads pinned before SMW writes
    if (c + 1 < nchunk) LOADK(c + 1);   // safe: QK consumed kf at issue
    LOADV(c);                           // safe: PV consumed vf at issue
    SMW(c, qA, mA, lA, zA, sP[0][c & 1], aA);
    SMW(c, qB, mB, lB, zB, sP[1][c & 1], aB);
    asm volatile("" ::: "memory");      // P(c) writes pinned before next PV
  }

  { // drain: PV(nchunk-1) from the last-written buffer
    __builtin_amdgcn_s_setprio(1);
    PV((nchunk - 1) & 1);
    __builtin_amdgcn_s_setprio(0);
  }
#undef QK
#undef LOADK
#undef LOADV

  // one-time sum reduction across the 4 quad-lanes of each row
  lA += __shfl_xor(lA, 16, 64); lA += __shfl_xor(lA, 32, 64);
  lB += __shfl_xor(lB, 16, 64); lB += __shfl_xor(lB, 32, 64);
  float invA[4], invB[4];
  for (int r = 0; r < 4; ++r) {
    invA[r] = 1.0f / __shfl(lA, quad * 4 + r, 16);
    invB[r] = 1.0f / __shfl(lB, quad * 4 + r, 16);
  }
  for (int dc = 0; dc < 4; ++dc)
    for (int r = 0; r < 4; ++r) {
      size_t rowA = (size_t)b * 2048 + qA + quad * 4 + r;
      size_t rowB = (size_t)b * 2048 + qB + quad * 4 + r;
      Z[rowA * 1024 + h * 64 + dc * 16 + lq] = f2b(zA[dc][r] * invA[r]);
      Z[rowB * 1024 + h * 64 + dc * 16 + lq] = f2b(zB[dc][r] * invB[r]);
    }
}

// ---------------------------------------------------------------------------
// Launch
// ---------------------------------------------------------------------------
extern "C" void kernel_launch(void* const* d_in, const int* in_sizes, int n_in,
                              void* d_out, int out_size, void* d_ws, size_t ws_size,
                              hipStream_t stream) {
  const float* x  = (const float*)d_in[0];
  const float* WQ = (const float*)d_in[1];
  const float* bQ = (const float*)d_in[2];
  const float* WK = (const float*)d_in[3];
  const float* bK = (const float*)d_in[4];
  const float* WV = (const float*)d_in[5];
  const float* WO = (const float*)d_in[6];
  const float* bV = (const float*)d_in[7];
  const float* bO = (const float*)d_in[8];
  float* out = (float*)d_out;

  uint8_t* ws = (uint8_t*)d_ws;
  u16*   xb    = (u16*)(ws);                       //  8 MB  [4096][1024] bf16 x
  u16*   WTqkv = (u16*)(ws + 8388608);             //  6 MB
  u16*   WOT   = (u16*)(ws + 14680064);            //  2 MB
  u16*   QKV   = (u16*)(ws + 16777216);            // 24 MB (V third unused)
  u16*   Zb    = (u16*)(ws + 41943040);            //  8 MB
  float* bqkv  = (float*)(ws + 50331648);          // 12 KB
  float* bsum  = (float*)(ws + 50343936);          //  4 KB
  u16*   VTv   = (u16*)(ws + 50348032);            //  8 MB V^T (own region)

  // fused prep: conv_x + 3x convT_w + convT_wo + conv_bias
  prep<<<5136, 256, 0, stream>>>(x, xb, WQ, WK, WV, WO, WTqkv, WOT,
                                 bQ, bK, bV, bO, bqkv, bsum);
  // QKV projection (Q cols pre-scaled by 0.125), fused V-transpose epilogue:
  // 128x128 tile, BK=32, 768 blocks = exactly 3/CU
  gemm_bt<false, 128, 128, 256, true, 32><<<dim3(24, 32), 256, 0, stream>>>(
      xb, WTqkv, bqkv, (void*)QKV, VTv, 3072, 1024, 1024);
  // attention: round-13 proven config, 2048 one-wave blocks
  attn_fwd<<<dim3(2048, 1, 1), 64, 0, stream>>>(QKV, VTv, Zb);
  // output projection: 128x64 tile, BK=64 (2 half-stages), 512 blocks = 2/CU
  gemm_bt<true, 128, 64, 256, false, 64><<<dim3(16, 32), 256, 0, stream>>>(
      Zb, WOT, bsum, (void*)out, nullptr, 1024, 1024, 0);
}